// Round 1
// baseline (1171.201 us; speedup 1.0000x reference)
//
#include <hip/hip_runtime.h>

// TrainableTokensLayer: out[b,s,:] = W[x[b,s],:] + sum_{i: token_indices[i]==x[b,s]} delta[i,:]
// where delta[i,d] = delta_values[d*N_TRAIN + i]  (COO values reshaped (EMBED,N_TRAIN).T)
//
// Strategy: pure gather with on-the-fly sparse patch. token_indices is sorted,
// so a binary search (block-uniform, no divergence) finds the duplicate range.
// Memory-bound: ~268 MB total traffic -> ~43us floor at 6.3 TB/s.

#define EMBED 2048
#define N_TRAIN 256

__global__ __launch_bounds__(256) void tt_gather_kernel(
    const int*   __restrict__ x,        // [n_rows]
    const float* __restrict__ W,        // [VOCAB, EMBED]
    const float* __restrict__ delta,    // [EMBED * N_TRAIN], delta[i][d] = delta[d*N_TRAIN + i]
    const int*   __restrict__ tok,      // [N_TRAIN], sorted
    float*       __restrict__ out,      // [n_rows, EMBED]
    int n_rows)
{
    __shared__ int s_tok[N_TRAIN];
    const int tid = threadIdx.x;
    s_tok[tid] = tok[tid];   // blockDim.x == N_TRAIN == 256
    __syncthreads();

    for (int row = blockIdx.x; row < n_rows; row += gridDim.x) {
        const int token = x[row];

        // lower_bound
        int lo = 0, hi = N_TRAIN;
        while (lo < hi) { int mid = (lo + hi) >> 1; if (s_tok[mid] < token) lo = mid + 1; else hi = mid; }
        const int start = lo;
        // upper_bound (continue from lower bound)
        hi = N_TRAIN;
        while (lo < hi) { int mid = (lo + hi) >> 1; if (s_tok[mid] <= token) lo = mid + 1; else hi = mid; }
        const int end = lo;

        const float* wrow = W + (size_t)token * EMBED;
        float*       orow = out + (size_t)row * EMBED;

        // 2048 floats / 256 threads = 8 floats/thread = 2x float4, coalesced
        #pragma unroll
        for (int c = 0; c < 2; ++c) {
            const int d = c * 1024 + tid * 4;
            float4 v = *(const float4*)(wrow + d);
            if (start < end) {              // block-uniform branch, ~0.2% of blocks
                for (int i = start; i < end; ++i) {
                    v.x += delta[(size_t)(d + 0) * N_TRAIN + i];
                    v.y += delta[(size_t)(d + 1) * N_TRAIN + i];
                    v.z += delta[(size_t)(d + 2) * N_TRAIN + i];
                    v.w += delta[(size_t)(d + 3) * N_TRAIN + i];
                }
            }
            *(float4*)(orow + d) = v;
        }
    }
}

extern "C" void kernel_launch(void* const* d_in, const int* in_sizes, int n_in,
                              void* d_out, int out_size, void* d_ws, size_t ws_size,
                              hipStream_t stream) {
    const int*   x     = (const int*)d_in[0];    // [B*S] int32
    const float* W     = (const float*)d_in[1];  // [VOCAB*EMBED] f32
    const float* delta = (const float*)d_in[2];  // [N_TRAIN*EMBED] f32
    const int*   tok   = (const int*)d_in[3];    // [N_TRAIN] int32

    float* out = (float*)d_out;
    const int n_rows = in_sizes[0];              // B*S = 16384

    tt_gather_kernel<<<n_rows, 256, 0, stream>>>(x, W, delta, tok, out, n_rows);
}